// Round 3
// baseline (437.829 us; speedup 1.0000x reference)
//
#include <hip/hip_runtime.h>
#include <hip/hip_bf16.h>

#define HID 128
#define NRBF 20
#define KNN 16
#define NNODE 4096
#define NBATCH 8

typedef __attribute__((ext_vector_type(8))) short short8;
typedef __attribute__((ext_vector_type(4))) float f32x4;

__device__ __forceinline__ short f2bf(float x) {
  __hip_bfloat16 b = __float2bfloat16(x);   // RNE, compiler may pack v_cvt_pk
  return __builtin_bit_cast(short, b);
}
__device__ __forceinline__ float silu_f(float x) {
  return x / (1.0f + __expf(-x));
}
// convert 8 consecutive f32 -> short8 of bf16
__device__ __forceinline__ short8 cv8(const float* p) {
  f32x4 a = *(const f32x4*)p;
  f32x4 b = *(const f32x4*)(p + 4);
  short8 r;
  r[0]=f2bf(a[0]); r[1]=f2bf(a[1]); r[2]=f2bf(a[2]); r[3]=f2bf(a[3]);
  r[4]=f2bf(b[0]); r[5]=f2bf(b[1]); r[6]=f2bf(b[2]); r[7]=f2bf(b[3]);
  return r;
}

// ---------------------------------------------------------------------------
// Kernel 1: exact kNN (top-16 by distance, stable index tiebreak), f32
// one wave per node; threshold = 16th smallest of per-lane strip minima
// ---------------------------------------------------------------------------
__global__ __launch_bounds__(512)
void knn_kernel(const float* __restrict__ pos,
                int* __restrict__ eidx, float* __restrict__ edist)
{
  __shared__ float posL[NNODE * 3];
  __shared__ float d2b[8][128];
  __shared__ int   jb[8][128];
  __shared__ int   cntL[8];

  const int tid  = threadIdx.x;
  const int wv   = tid >> 6;
  const int lane = tid & 63;
  const int b    = blockIdx.x >> 7;     // 128 blocks per batch
  const int grp  = blockIdx.x & 127;

  const float* pb = pos + (size_t)b * NNODE * 3;
  for (int idx = tid; idx < NNODE * 3; idx += 512)
    posL[idx] = pb[idx];
  __syncthreads();

  for (int itn = 0; itn < 4; ++itn) {
    const int i = grp * 32 + wv * 4 + itn;
    const float pix = posL[i*3], piy = posL[i*3+1], piz = posL[i*3+2];

    // pass 1: per-lane strip minima (numpy-exact f32 arithmetic, no FMA)
    float vmin = 3.0e38f;
    for (int t = 0; t < 64; ++t) {
      const int j = t * 64 + lane;
      float dx = __fsub_rn(pix, posL[j*3]);
      float dy = __fsub_rn(piy, posL[j*3+1]);
      float dz = __fsub_rn(piz, posL[j*3+2]);
      float d2 = __fadd_rn(__fadd_rn(__fmul_rn(dx,dx), __fmul_rn(dy,dy)), __fmul_rn(dz,dz));
      if (j == i) d2 = 3.0e38f;
      vmin = fminf(vmin, d2);
    }

    // bitonic sort the 64 lane minima (ascending); T = element 15
    float v = vmin;
    #pragma unroll
    for (int k = 2; k <= 64; k <<= 1) {
      #pragma unroll
      for (int jj = k >> 1; jj > 0; jj >>= 1) {
        float o = __shfl_xor(v, jj);
        const bool up   = ((lane & k) == 0);
        const bool lowl = ((lane & jj) == 0);
        float mn = fminf(v, o), mx = fmaxf(v, o);
        v = (up == lowl) ? mn : mx;
      }
    }
    const float T = __shfl(v, 15);   // >= true 16th smallest (16 strips have min <= T)

    if (lane == 0) cntL[wv] = 0;
    // pass 2: compact candidates with d2 <= T (expected ~20-40)
    for (int t = 0; t < 64; ++t) {
      const int j = t * 64 + lane;
      float dx = __fsub_rn(pix, posL[j*3]);
      float dy = __fsub_rn(piy, posL[j*3+1]);
      float dz = __fsub_rn(piz, posL[j*3+2]);
      float d2 = __fadd_rn(__fadd_rn(__fmul_rn(dx,dx), __fmul_rn(dy,dy)), __fmul_rn(dz,dz));
      bool ok = (j != i) && (d2 <= T);
      if (ok) {
        int p = atomicAdd(&cntL[wv], 1);
        if (p < 128) { d2b[wv][p] = d2; jb[wv][p] = j; }
      }
    }
    int cnt = cntL[wv];
    if (cnt > 128) cnt = 128;

    // exact stable rank selection (ties -> lower index, matches top_k)
    for (int s = lane; s < cnt; s += 64) {
      float dm = d2b[wv][s]; int jm = jb[wv][s];
      int rank = 0;
      for (int c = 0; c < cnt; ++c) {
        float dc = d2b[wv][c]; int jc = jb[wv][c];
        if (dc < dm || (dc == dm && jc < jm)) ++rank;
      }
      if (rank < KNN) {
        size_t base = ((size_t)b * NNODE + i) * KNN;
        eidx[base + rank]  = b * NNODE + jm;          // global row index
        edist[base + rank] = sqrtf(__fadd_rn(dm, 1e-8f));
      }
    }
  }
}

// ---------------------------------------------------------------------------
// Kernel 2: edge MLP (K=288 bf16 MFMA) + cutoff mask + per-node aggregate
// one wave per node (16 edges); weights transposed->bf16 in LDS; agg f32
// ---------------------------------------------------------------------------
#define ENPW 16

__global__ __launch_bounds__(256)
void edge_kernel(const float* __restrict__ h,
                 const int* __restrict__ eidx, const float* __restrict__ edist,
                 const float* __restrict__ ew1, const float* __restrict__ eb1,
                 const float* __restrict__ ew2, const float* __restrict__ eb2,
                 float* __restrict__ agg)
{
  __shared__ __attribute__((aligned(16))) short ewt1[128][296]; // [n][k] transposed
  __shared__ __attribute__((aligned(16))) short ewt2[128][136];
  __shared__ __attribute__((aligned(16))) short m1s[4][2048];   // per-wave 16x128 swizzled

  const int tid = threadIdx.x;
  for (int idx = tid; idx < 288 * 128; idx += 256) {
    int k = idx >> 7, n = idx & 127;
    ewt1[n][k] = (k < 276) ? f2bf(ew1[k * 128 + n]) : (short)0;
  }
  for (int idx = tid; idx < 128 * 128; idx += 256) {
    int k = idx >> 7, n = idx & 127;
    ewt2[n][k] = f2bf(ew2[k * 128 + n]);
  }
  __syncthreads();

  const int wv = tid >> 6, lane = tid & 63;
  const int lo = lane & 15, hi = lane >> 4;
  short* m1w = &m1s[wv][0];

  float b1v[8], b2v[8];
  #pragma unroll
  for (int nf = 0; nf < 8; ++nf) {
    b1v[nf] = eb1[nf * 16 + lo];
    b2v[nf] = eb2[nf * 16 + lo];
  }
  const f32x4 zero4 = {0.f, 0.f, 0.f, 0.f};

  for (int it = 0; it < ENPW; ++it) {
    const int node = (blockIdx.x * 4 + wv) * ENPW + it;   // 0..32767
    int jg = eidx[(size_t)node * KNN + lo];
    jg &= (NBATCH * NNODE - 1);                 // sanitize: never fault on bad idx
    const float de = edist[(size_t)node * KNN + lo];

    const float* hi_p = h + (size_t)node * HID;
    const float* hj_p = h + (size_t)jg * HID;
    short8 aI[4], aJ[4];
    #pragma unroll
    for (int kc = 0; kc < 4; ++kc) {
      aI[kc] = cv8(hi_p + kc*32 + hi*8);
      aJ[kc] = cv8(hj_p + kc*32 + hi*8);
    }
    short8 aR;
    #pragma unroll
    for (int e = 0; e < 8; ++e) {
      const int r = hi * 8 + e;
      float val = 0.0f;
      if (r < NRBF) {
        const float cr = (float)(r * (5.0 / 19.0));
        float tt = __fsub_rn(de, cr);
        val = __expf(-16.0f * __fmul_rn(tt, tt));
      }
      aR[e] = f2bf(val);
    }

    f32x4 acc1[8];
    #pragma unroll
    for (int nf = 0; nf < 8; ++nf) acc1[nf] = zero4;
    #pragma unroll
    for (int kc = 0; kc < 9; ++kc) {
      short8 a = (kc < 4) ? aI[kc] : ((kc < 8) ? aJ[kc - 4] : aR);
      #pragma unroll
      for (int nf = 0; nf < 8; ++nf) {
        short8 bfrag = *(const short8*)&ewt1[nf*16 + lo][kc*32 + hi*8];
        acc1[nf] = __builtin_amdgcn_mfma_f32_16x16x32_bf16(a, bfrag, acc1[nf], 0, 0, 0);
      }
    }

    // bias + SiLU -> m1 (bf16) into XOR-swizzled per-wave LDS tile [16][128]
    #pragma unroll
    for (int nf = 0; nf < 8; ++nf) {
      #pragma unroll
      for (int q = 0; q < 4; ++q) {
        float x = acc1[nf][q] + b1v[nf];
        float s = silu_f(x);
        int row = hi * 4 + q, col = nf * 16 + lo;
        int byteoff = ((row << 8) + (col << 1)) ^ ((row & 7) << 4);
        *(short*)((char*)m1w + byteoff) = f2bf(s);
      }
    }

    f32x4 acc2[8];
    #pragma unroll
    for (int nf = 0; nf < 8; ++nf) acc2[nf] = zero4;
    #pragma unroll
    for (int kc = 0; kc < 4; ++kc) {
      int byteA = ((lo << 8) + ((kc*32 + hi*8) << 1)) ^ ((lo & 7) << 4);
      short8 a = *(const short8*)((char*)m1w + byteA);
      #pragma unroll
      for (int nf = 0; nf < 8; ++nf) {
        short8 bfrag = *(const short8*)&ewt2[nf*16 + lo][kc*32 + hi*8];
        acc2[nf] = __builtin_amdgcn_mfma_f32_16x16x32_bf16(a, bfrag, acc2[nf], 0, 0, 0);
      }
    }

    float dq[4];
    #pragma unroll
    for (int q = 0; q < 4; ++q) dq[q] = edist[(size_t)node * KNN + hi*4 + q];
    #pragma unroll
    for (int nf = 0; nf < 8; ++nf) {
      float s = 0.0f;
      #pragma unroll
      for (int q = 0; q < 4; ++q) {
        float x = acc2[nf][q] + b2v[nf];
        float m = silu_f(x);
        s += (dq[q] < 5.0f) ? m : 0.0f;   // cutoff mask
      }
      s += __shfl_xor(s, 16);
      s += __shfl_xor(s, 32);
      if (hi == 0) agg[(size_t)node * HID + nf*16 + lo] = s;   // f32
    }
  }
}

// ---------------------------------------------------------------------------
// Kernel 3: node MLP (K=256 bf16 MFMA) + residual + LayerNorm, f32 I/O
// agg == out (in-place): each wave reads only its own 16 rows before writing
// ---------------------------------------------------------------------------
__global__ __launch_bounds__(256)
void node_kernel(const float* __restrict__ h, const float* agg,
                 const float* __restrict__ nw1, const float* __restrict__ nb1,
                 const float* __restrict__ nw2, const float* __restrict__ nb2,
                 const float* __restrict__ gam, const float* __restrict__ bet,
                 float* out)
{
  __shared__ __attribute__((aligned(16))) short w1t[128][264];
  __shared__ __attribute__((aligned(16))) short w2t[128][136];
  __shared__ __attribute__((aligned(16))) short m1s[4][2048];

  const int tid = threadIdx.x;
  for (int idx = tid; idx < 256 * 128; idx += 256) {
    int k = idx >> 7, n = idx & 127;
    w1t[n][k] = f2bf(nw1[k * 128 + n]);
  }
  for (int idx = tid; idx < 128 * 128; idx += 256) {
    int k = idx >> 7, n = idx & 127;
    w2t[n][k] = f2bf(nw2[k * 128 + n]);
  }
  __syncthreads();

  const int wv = tid >> 6, lane = tid & 63;
  const int lo = lane & 15, hi = lane >> 4;
  short* m1w = &m1s[wv][0];

  float b1v[8], b2v[8], gv[8], bv[8];
  #pragma unroll
  for (int nf = 0; nf < 8; ++nf) {
    b1v[nf] = nb1[nf*16 + lo];
    b2v[nf] = nb2[nf*16 + lo];
    gv[nf]  = gam[nf*16 + lo];
    bv[nf]  = bet[nf*16 + lo];
  }
  const f32x4 zero4 = {0.f, 0.f, 0.f, 0.f};

  const int row0 = (blockIdx.x * 4 + wv) * 16;   // 0..32752

  const float* hrow = h   + (size_t)(row0 + lo) * HID;
  const float* arow = agg + (size_t)(row0 + lo) * HID;

  f32x4 acc1[8];
  #pragma unroll
  for (int nf = 0; nf < 8; ++nf) acc1[nf] = zero4;
  #pragma unroll
  for (int kc = 0; kc < 8; ++kc) {
    short8 a = (kc < 4) ? cv8(hrow + kc*32 + hi*8)
                        : cv8(arow + (kc - 4)*32 + hi*8);
    #pragma unroll
    for (int nf = 0; nf < 8; ++nf) {
      short8 bfrag = *(const short8*)&w1t[nf*16 + lo][kc*32 + hi*8];
      acc1[nf] = __builtin_amdgcn_mfma_f32_16x16x32_bf16(a, bfrag, acc1[nf], 0, 0, 0);
    }
  }

  #pragma unroll
  for (int nf = 0; nf < 8; ++nf) {
    #pragma unroll
    for (int q = 0; q < 4; ++q) {
      float x = acc1[nf][q] + b1v[nf];
      float s = silu_f(x);
      int row = hi * 4 + q, col = nf * 16 + lo;
      int byteoff = ((row << 8) + (col << 1)) ^ ((row & 7) << 4);
      *(short*)((char*)m1w + byteoff) = f2bf(s);
    }
  }

  f32x4 acc2[8];
  #pragma unroll
  for (int nf = 0; nf < 8; ++nf) acc2[nf] = zero4;
  #pragma unroll
  for (int kc = 0; kc < 4; ++kc) {
    int byteA = ((lo << 8) + ((kc*32 + hi*8) << 1)) ^ ((lo & 7) << 4);
    short8 a = *(const short8*)((char*)m1w + byteA);
    #pragma unroll
    for (int nf = 0; nf < 8; ++nf) {
      short8 bfrag = *(const short8*)&w2t[nf*16 + lo][kc*32 + hi*8];
      acc2[nf] = __builtin_amdgcn_mfma_f32_16x16x32_bf16(a, bfrag, acc2[nf], 0, 0, 0);
    }
  }

  // x = h + update (h added in exact f32); LayerNorm over 128 dims
  float xv[4][8];
  #pragma unroll
  for (int nf = 0; nf < 8; ++nf) {
    #pragma unroll
    for (int q = 0; q < 4; ++q) {
      xv[q][nf] = acc2[nf][q] + b2v[nf]
                + h[(size_t)(row0 + hi*4 + q) * HID + nf*16 + lo];
    }
  }

  #pragma unroll
  for (int q = 0; q < 4; ++q) {
    float s = 0.0f;
    #pragma unroll
    for (int nf = 0; nf < 8; ++nf) s += xv[q][nf];
    s += __shfl_xor(s, 1); s += __shfl_xor(s, 2);
    s += __shfl_xor(s, 4); s += __shfl_xor(s, 8);
    float mu = s * 0.0078125f;
    float t = 0.0f;
    #pragma unroll
    for (int nf = 0; nf < 8; ++nf) { float d = xv[q][nf] - mu; t += d * d; }
    t += __shfl_xor(t, 1); t += __shfl_xor(t, 2);
    t += __shfl_xor(t, 4); t += __shfl_xor(t, 8);
    float inv = 1.0f / sqrtf(t * 0.0078125f + 1e-5f);
    #pragma unroll
    for (int nf = 0; nf < 8; ++nf) {
      float y = (xv[q][nf] - mu) * inv * gv[nf] + bv[nf];
      out[(size_t)(row0 + hi*4 + q) * HID + nf*16 + lo] = y;
    }
  }
}

// ---------------------------------------------------------------------------
extern "C" void kernel_launch(void* const* d_in, const int* in_sizes, int n_in,
                              void* d_out, int out_size, void* d_ws, size_t ws_size,
                              hipStream_t stream) {
  (void)in_sizes; (void)n_in; (void)out_size;
  const float* h   = (const float*)d_in[0];
  const float* pos = (const float*)d_in[1];
  const float* ew1 = (const float*)d_in[2];
  const float* eb1 = (const float*)d_in[3];
  const float* ew2 = (const float*)d_in[4];
  const float* eb2 = (const float*)d_in[5];
  const float* nw1 = (const float*)d_in[6];
  const float* nb1 = (const float*)d_in[7];
  const float* nw2 = (const float*)d_in[8];
  const float* nb2 = (const float*)d_in[9];
  const float* gam = (const float*)d_in[10];
  const float* bet = (const float*)d_in[11];

  // ws: eidx 2MB | edist 2MB.  agg (f32 [8,4096,128]) lives in d_out; node in-place.
  const size_t need = (size_t)NBATCH * NNODE * KNN * 8;   // 4 MB
  if (ws_size < need) return;   // clean finite diagnostic instead of a fault

  char* wsp = (char*)d_ws;
  int*   eidx  = (int*)wsp;
  float* edist = (float*)(wsp + (size_t)NBATCH * NNODE * KNN * 4);
  float* agg   = (float*)d_out;

  knn_kernel<<<dim3(1024), dim3(512), 0, stream>>>(pos, eidx, edist);
  edge_kernel<<<dim3(512), dim3(256), 0, stream>>>(h, eidx, edist, ew1, eb1, ew2, eb2, agg);
  node_kernel<<<dim3(512), dim3(256), 0, stream>>>(h, agg, nw1, nb1, nw2, nb2, gam, bet,
                                                   (float*)d_out);
}